// Round 1
// baseline (960.307 us; speedup 1.0000x reference)
//
#include <hip/hip_runtime.h>

// Row-wise cosine similarity mean:
//   out = mean_i [ dot(A_i,B_i) / (max(||A_i||,eps) * max(||B_i||,eps)) ]
// A,B: (N=1048576, D=128) fp32. Memory-bound: 1.074 GB read, ~170us floor.
//
// Structure: 8 lanes per row (each lane covers 16 floats = 4 float4s).
//  - 8 rows per wave-iteration, 3-stage butterfly (xor 1,2,4) per value.
//  - Blocks own contiguous row chunks -> sequential streaming.
//  - 8 independent 16B loads in flight per lane before any dependent op.

#define EPS 1e-12f
#define D 128

constexpr int BLOCKS  = 2048;
constexpr int THREADS = 256;                       // 4 waves/block
constexpr int WAVES   = THREADS / 64;
constexpr int ROWS_PER_WAVE_ITER  = 8;             // 8 groups x 8 lanes
constexpr int ROWS_PER_BLOCK_ITER = WAVES * ROWS_PER_WAVE_ITER;  // 32

__device__ __forceinline__ void dot3(const float4& a, const float4& b,
                                     float& dab, float& daa, float& dbb)
{
    dab += a.x * b.x + a.y * b.y + a.z * b.z + a.w * b.w;
    daa += a.x * a.x + a.y * a.y + a.z * a.z + a.w * a.w;
    dbb += b.x * b.x + b.y * b.y + b.z * b.z + b.w * b.w;
}

__global__ __launch_bounds__(THREADS) void cos_partials(
    const float* __restrict__ A, const float* __restrict__ B,
    float* __restrict__ partials, int nrows)
{
    const int lane = threadIdx.x & 63;
    const int wid  = threadIdx.x >> 6;     // wave in block
    const int g    = lane >> 3;            // group (row slot) 0..7
    const int sub  = lane & 7;             // lane within 8-lane group

    // Contiguous chunk of rows per block.
    const int rows_per_block = (nrows + gridDim.x - 1) / gridDim.x;  // 512
    const int base = blockIdx.x * rows_per_block;
    const int lim  = min(base + rows_per_block, nrows);

    float acc = 0.0f;

    for (int r0 = base + wid * ROWS_PER_WAVE_ITER + g; r0 < lim;
         r0 += ROWS_PER_BLOCK_ITER) {
        // group-uniform row (g is constant within the 8-lane group)
        const size_t row = (size_t)r0;
        const float4* Ar = (const float4*)(A + row * D);
        const float4* Br = (const float4*)(B + row * D);

        // 8 independent 16B loads, issued before any dependent compute.
        // For fixed k, a group's 8 lanes read 128B contiguous; groups are
        // consecutive rows -> cache-line-perfect coalescing.
        const float4 a0 = Ar[sub];
        const float4 a1 = Ar[sub + 8];
        const float4 a2 = Ar[sub + 16];
        const float4 a3 = Ar[sub + 24];
        const float4 b0 = Br[sub];
        const float4 b1 = Br[sub + 8];
        const float4 b2 = Br[sub + 16];
        const float4 b3 = Br[sub + 24];

        float dab = 0.f, daa = 0.f, dbb = 0.f;
        dot3(a0, b0, dab, daa, dbb);
        dot3(a1, b1, dab, daa, dbb);
        dot3(a2, b2, dab, daa, dbb);
        dot3(a3, b3, dab, daa, dbb);

        // 3-stage butterfly within the 8-lane group (xor < 8 stays in group)
        #pragma unroll
        for (int off = 1; off <= 4; off <<= 1) {
            dab += __shfl_xor(dab, off, 64);
            daa += __shfl_xor(daa, off, 64);
            dbb += __shfl_xor(dbb, off, 64);
        }

        if (sub == 0) {
            acc += dab / fmaxf(sqrtf(daa), EPS) / fmaxf(sqrtf(dbb), EPS);
        }
    }

    // Wave reduce: nonzero acc only at lanes 0,8,...,56 (sub==0).
    // Butterfly over offsets 8,16,32 sums those 8 values.
    #pragma unroll
    for (int off = 8; off <= 32; off <<= 1) acc += __shfl_xor(acc, off, 64);

    __shared__ float wsum[WAVES];
    if (lane == 0) wsum[wid] = acc;
    __syncthreads();
    if (threadIdx.x == 0) {
        float s = 0.f;
        #pragma unroll
        for (int w = 0; w < WAVES; ++w) s += wsum[w];
        partials[blockIdx.x] = s;
    }
}

__global__ __launch_bounds__(256) void final_reduce(
    const float* __restrict__ partials, float* __restrict__ out,
    int n, double invN)
{
    __shared__ double tsum[256];
    double acc = 0.0;
    for (int i = threadIdx.x; i < n; i += blockDim.x) acc += (double)partials[i];
    tsum[threadIdx.x] = acc;
    __syncthreads();

    for (int s = 128; s > 0; s >>= 1) {
        if (threadIdx.x < s) tsum[threadIdx.x] += tsum[threadIdx.x + s];
        __syncthreads();
    }
    if (threadIdx.x == 0) out[0] = (float)(tsum[0] * invN);
}

extern "C" void kernel_launch(void* const* d_in, const int* in_sizes, int n_in,
                              void* d_out, int out_size, void* d_ws, size_t ws_size,
                              hipStream_t stream) {
    const float* A = (const float*)d_in[0];
    const float* B = (const float*)d_in[1];
    float* out = (float*)d_out;
    float* partials = (float*)d_ws;           // BLOCKS * 4 bytes

    const int nrows = in_sizes[0] / D;        // 1048576

    cos_partials<<<BLOCKS, THREADS, 0, stream>>>(A, B, partials, nrows);
    final_reduce<<<1, 256, 0, stream>>>(partials, out, BLOCKS, 1.0 / (double)nrows);
}